// Round 1
// baseline (123.108 us; speedup 1.0000x reference)
//
#include <hip/hip_runtime.h>
#include <hip/hip_bf16.h>

#define LOG2E 1.4426950408889634f

#if __has_builtin(__builtin_amdgcn_exp2f)
#define EXP2F(x) __builtin_amdgcn_exp2f(x)
#else
#define EXP2F(x) exp2f(x)
#endif

// ---------------------------------------------------------------------------
// Kernel 1: one block of 64 threads.
// Computes Kzz (64x64), its Cholesky L (in LDS), solves L^T W = U (W = L^-T U,
// which equals inv(Kzz) @ L @ U), and writes a packed per-m struct to ws:
//   ws[m*8 + 0..2] = Z[m]/ell
//   ws[m*8 + 3]    = -0.5*log2(e)*||Z[m]/ell||^2
//   ws[m*8 + 4]    = sf^2 * W[m][0]
//   ws[m*8 + 5]    = sf^2 * W[m][1]
//   ws[m*8 + 6..7] = 0 (pad so kernel 2 can read two float4 per m)
// ---------------------------------------------------------------------------
__global__ void gp_precompute(const float* __restrict__ Z, const float* __restrict__ U,
                              const float* __restrict__ sf_p, const float* __restrict__ ell_p,
                              float* __restrict__ ws) {
    __shared__ float A[64][65];   // Kzz then (lower) Cholesky factor, padded
    __shared__ float Zs[64][3];
    __shared__ float W[64][2];
    const int tid = threadIdx.x;   // 64 threads
    const float sf   = sf_p[0];
    const float ell  = ell_p[0];
    const float inv_ell = 1.0f / ell;
    const float sf2  = sf * sf;

    const float z0 = Z[tid * 3 + 0] * inv_ell;
    const float z1 = Z[tid * 3 + 1] * inv_ell;
    const float z2 = Z[tid * 3 + 2] * inv_ell;
    Zs[tid][0] = z0; Zs[tid][1] = z1; Zs[tid][2] = z2;
    __syncthreads();

    // Row tid of Kzz
    for (int j = 0; j < 64; ++j) {
        float dx = z0 - Zs[j][0];
        float dy = z1 - Zs[j][1];
        float dz = z2 - Zs[j][2];
        float sq = dx * dx + dy * dy + dz * dz;
        A[tid][j] = sf2 * __expf(-0.5f * sq);
    }
    __syncthreads();

    // In-place right-looking Cholesky (lower triangle), parallel over rows.
    for (int k = 0; k < 64; ++k) {
        if (tid == k) A[k][k] = sqrtf(A[k][k]);
        __syncthreads();
        if (tid > k) A[tid][k] /= A[k][k];
        __syncthreads();
        if (tid > k) {
            const float lik = A[tid][k];
            for (int j = k + 1; j <= tid; ++j) A[tid][j] -= lik * A[j][k];
        }
        __syncthreads();
    }

    // Back-substitution: L^T W = U  (upper-triangular solve, bottom-up).
    // O=2 columns -> two threads each handle one column sequentially.
    if (tid < 2) {
        const int o = tid;
        for (int i = 63; i >= 0; --i) {
            float s = U[i * 2 + o];
            for (int j = i + 1; j < 64; ++j) s -= A[j][i] * W[j][o];
            W[i][o] = s / A[i][i];
        }
    }
    __syncthreads();

    const float dm = -0.5f * LOG2E * (z0 * z0 + z1 * z1 + z2 * z2);
    ws[tid * 8 + 0] = z0;
    ws[tid * 8 + 1] = z1;
    ws[tid * 8 + 2] = z2;
    ws[tid * 8 + 3] = dm;
    ws[tid * 8 + 4] = sf2 * W[tid][0];
    ws[tid * 8 + 5] = sf2 * W[tid][1];
    ws[tid * 8 + 6] = 0.0f;
    ws[tid * 8 + 7] = 0.0f;
}

// ---------------------------------------------------------------------------
// Kernel 2: out[i,:] = sum_m sf^2 * exp(-||x_i/ell - z_m/ell||^2 / 2) * W[m,:]
// Uses exp2 with log2(e) pre-folded:
//   arg = c_i + d_m + (log2e * x_i/ell) . (z_m/ell)
//   c_i = -0.5*log2e*||x_i/ell||^2 ; d_m = -0.5*log2e*||z_m/ell||^2
// 4 points per thread amortize the two broadcast ds_read_b128 per m.
// ---------------------------------------------------------------------------
__global__ __launch_bounds__(256) void gp_forward(const float* __restrict__ X,
                                                  const float* __restrict__ ws,
                                                  const float* __restrict__ ell_p,
                                                  float* __restrict__ out, int n) {
    __shared__ float4 P[128];   // 64 structs of {zs0,zs1,zs2,dm | w0,w1,0,0}
    for (int i = threadIdx.x; i < 128; i += 256)
        P[i] = ((const float4*)ws)[i];
    const float inv_ell = 1.0f / ell_p[0];
    __syncthreads();

    const int base = blockIdx.x * (256 * 4) + threadIdx.x;

    float xt0[4], xt1[4], xt2[4], c[4];
#pragma unroll
    for (int p = 0; p < 4; ++p) {
        int i = base + p * 256;
        int ii = (i < n) ? i : 0;            // clamp; result masked on store
        float xs0 = X[ii * 3 + 0] * inv_ell;
        float xs1 = X[ii * 3 + 1] * inv_ell;
        float xs2 = X[ii * 3 + 2] * inv_ell;
        c[p]  = -0.5f * LOG2E * (xs0 * xs0 + xs1 * xs1 + xs2 * xs2);
        xt0[p] = xs0 * LOG2E;
        xt1[p] = xs1 * LOG2E;
        xt2[p] = xs2 * LOG2E;
    }

    float acc0[4] = {0.f, 0.f, 0.f, 0.f};
    float acc1[4] = {0.f, 0.f, 0.f, 0.f};

#pragma unroll 4
    for (int m = 0; m < 64; ++m) {
        const float4 a = P[2 * m + 0];   // zs0, zs1, zs2, dm
        const float4 b = P[2 * m + 1];   // w0, w1, pad, pad
#pragma unroll
        for (int p = 0; p < 4; ++p) {
            float arg = fmaf(xt0[p], a.x,
                        fmaf(xt1[p], a.y,
                        fmaf(xt2[p], a.z, c[p] + a.w)));
            float e = EXP2F(arg);
            acc0[p] = fmaf(e, b.x, acc0[p]);
            acc1[p] = fmaf(e, b.y, acc1[p]);
        }
    }

    float2* out2 = (float2*)out;
#pragma unroll
    for (int p = 0; p < 4; ++p) {
        int i = base + p * 256;
        if (i < n) out2[i] = make_float2(acc0[p], acc1[p]);
    }
}

extern "C" void kernel_launch(void* const* d_in, const int* in_sizes, int n_in,
                              void* d_out, int out_size, void* d_ws, size_t ws_size,
                              hipStream_t stream) {
    // setup_inputs order: t, X, Z, U, sf, ell
    const float* X    = (const float*)d_in[1];
    const float* Z    = (const float*)d_in[2];
    const float* U    = (const float*)d_in[3];
    const float* sf   = (const float*)d_in[4];
    const float* ell  = (const float*)d_in[5];
    float* out = (float*)d_out;
    float* ws  = (float*)d_ws;
    const int N = in_sizes[1] / 3;

    gp_precompute<<<1, 64, 0, stream>>>(Z, U, sf, ell, ws);

    const int PTS_PER_BLOCK = 256 * 4;
    const int blocks = (N + PTS_PER_BLOCK - 1) / PTS_PER_BLOCK;
    gp_forward<<<blocks, 256, 0, stream>>>(X, ws, ell, out, N);
}

// Round 2
// 94.645 us; speedup vs baseline: 1.3007x; 1.3007x over previous
//
#include <hip/hip_runtime.h>
#include <hip/hip_bf16.h>

#define LOG2E 1.4426950408889634f

#if __has_builtin(__builtin_amdgcn_exp2f)
#define EXP2F(x) __builtin_amdgcn_exp2f(x)
#else
#define EXP2F(x) exp2f(x)
#endif

// ---------------------------------------------------------------------------
// Kernel 1: ONE wave (64 threads). Register-resident Cholesky.
// Lane l owns row l of Kzz in r[0..63] (fully unrolled -> all register
// indices compile-time). Column-k broadcasts via __shfl with constant lane
// (v_readlane, no LDS). Then L is spilled once to LDS (stride 65,
// conflict-free) and L^T W = U is solved with the 64-step column sweep:
// per step one conflict-free row read + 2 fma. Replaces the previous
// LDS-latency-serialized version (107 us -> target <10 us).
//
// ws layout (per m, 8 floats):
//   [0..2] = Z[m]/ell, [3] = -0.5*log2e*||Z[m]/ell||^2,
//   [4] = sf^2*W[m][0], [5] = sf^2*W[m][1], [6..7] = pad
// ---------------------------------------------------------------------------
__global__ void gp_precompute(const float* __restrict__ Z, const float* __restrict__ U,
                              const float* __restrict__ sf_p, const float* __restrict__ ell_p,
                              float* __restrict__ ws) {
    __shared__ float Lsh[64 * 65];
    const int lane = threadIdx.x;          // 64 threads = 1 wave
    const float sf  = sf_p[0];
    const float ell = ell_p[0];
    const float inv_ell = 1.0f / ell;
    const float sf2 = sf * sf;

    const float z0 = Z[lane * 3 + 0] * inv_ell;
    const float z1 = Z[lane * 3 + 1] * inv_ell;
    const float z2 = Z[lane * 3 + 2] * inv_ell;

    // Row `lane` of Kzz, entirely in registers.
    float r[64];
#pragma unroll
    for (int j = 0; j < 64; ++j) {
        float dx = z0 - __shfl(z0, j);
        float dy = z1 - __shfl(z1, j);
        float dz = z2 - __shfl(z2, j);
        float sq = dx * dx + dy * dy + dz * dz;
        r[j] = sf2 * EXP2F(-0.5f * LOG2E * sq);
    }

    // Right-looking Cholesky, fully unrolled. After iteration k, r[k] on
    // lane l holds L[l][k] (valid for l >= k; upper-triangle garbage is
    // never read: shfl sources are always lanes j > k).
    float rd[64];                          // 1/L[k][k], uniform across lanes
#pragma unroll
    for (int k = 0; k < 64; ++k) {
        float dk  = __shfl(r[k], k);       // A[k][k]
        float inv = 1.0f / sqrtf(dk);
        rd[k] = inv;
        float lk = r[k] * inv;             // lane l: L[l][k]  (l>=k valid)
        r[k] = lk;
#pragma unroll
        for (int j = k + 1; j < 64; ++j) {
            float ljk = __shfl(lk, j);     // L[j][k] -> v_readlane (const lane)
            r[j] = fmaf(-lk, ljk, r[j]);   // A[l][j] -= L[l][k]*L[j][k]
        }
    }

    // Spill L to LDS: row l at stride 65 -> both writes ((lane+j)%32) and
    // row-reads ((i+lane)%32) are conflict-free.
#pragma unroll
    for (int j = 0; j < 64; ++j) Lsh[lane * 65 + j] = r[j];
    __syncthreads();

    // Solve L^T W = U (column sweep): s_l = U[l][o] - sum_{j>i} L[j][l] W[j].
    float s0 = U[lane * 2 + 0];
    float s1 = U[lane * 2 + 1];
    float w0v = 0.0f, w1v = 0.0f;
#pragma unroll
    for (int i = 63; i >= 0; --i) {
        float w0 = __shfl(s0, i) * rd[i];  // W[i][0]
        float w1 = __shfl(s1, i) * rd[i];  // W[i][1]
        float a  = Lsh[i * 65 + lane];     // L[i][lane] (valid lane <= i)
        s0 = fmaf(-a, w0, s0);             // harmless garbage for lane >= i
        s1 = fmaf(-a, w1, s1);
        if (lane == i) { w0v = w0; w1v = w1; }
    }

    const float dm = -0.5f * LOG2E * (z0 * z0 + z1 * z1 + z2 * z2);
    ws[lane * 8 + 0] = z0;
    ws[lane * 8 + 1] = z1;
    ws[lane * 8 + 2] = z2;
    ws[lane * 8 + 3] = dm;
    ws[lane * 8 + 4] = sf2 * w0v;
    ws[lane * 8 + 5] = sf2 * w1v;
    ws[lane * 8 + 6] = 0.0f;
    ws[lane * 8 + 7] = 0.0f;
}

// ---------------------------------------------------------------------------
// Kernel 2 (unchanged from R1): out[i,:] = sum_m sf^2*exp2(c_i + d_m + xt.z)*W[m,:]
// ---------------------------------------------------------------------------
__global__ __launch_bounds__(256) void gp_forward(const float* __restrict__ X,
                                                  const float* __restrict__ ws,
                                                  const float* __restrict__ ell_p,
                                                  float* __restrict__ out, int n) {
    __shared__ float4 P[128];   // 64 structs of {zs0,zs1,zs2,dm | w0,w1,0,0}
    for (int i = threadIdx.x; i < 128; i += 256)
        P[i] = ((const float4*)ws)[i];
    const float inv_ell = 1.0f / ell_p[0];
    __syncthreads();

    const int base = blockIdx.x * (256 * 4) + threadIdx.x;

    float xt0[4], xt1[4], xt2[4], c[4];
#pragma unroll
    for (int p = 0; p < 4; ++p) {
        int i = base + p * 256;
        int ii = (i < n) ? i : 0;            // clamp; result masked on store
        float xs0 = X[ii * 3 + 0] * inv_ell;
        float xs1 = X[ii * 3 + 1] * inv_ell;
        float xs2 = X[ii * 3 + 2] * inv_ell;
        c[p]  = -0.5f * LOG2E * (xs0 * xs0 + xs1 * xs1 + xs2 * xs2);
        xt0[p] = xs0 * LOG2E;
        xt1[p] = xs1 * LOG2E;
        xt2[p] = xs2 * LOG2E;
    }

    float acc0[4] = {0.f, 0.f, 0.f, 0.f};
    float acc1[4] = {0.f, 0.f, 0.f, 0.f};

#pragma unroll 4
    for (int m = 0; m < 64; ++m) {
        const float4 a = P[2 * m + 0];   // zs0, zs1, zs2, dm
        const float4 b = P[2 * m + 1];   // w0, w1, pad, pad
#pragma unroll
        for (int p = 0; p < 4; ++p) {
            float arg = fmaf(xt0[p], a.x,
                        fmaf(xt1[p], a.y,
                        fmaf(xt2[p], a.z, c[p] + a.w)));
            float e = EXP2F(arg);
            acc0[p] = fmaf(e, b.x, acc0[p]);
            acc1[p] = fmaf(e, b.y, acc1[p]);
        }
    }

    float2* out2 = (float2*)out;
#pragma unroll
    for (int p = 0; p < 4; ++p) {
        int i = base + p * 256;
        if (i < n) out2[i] = make_float2(acc0[p], acc1[p]);
    }
}

extern "C" void kernel_launch(void* const* d_in, const int* in_sizes, int n_in,
                              void* d_out, int out_size, void* d_ws, size_t ws_size,
                              hipStream_t stream) {
    // setup_inputs order: t, X, Z, U, sf, ell
    const float* X    = (const float*)d_in[1];
    const float* Z    = (const float*)d_in[2];
    const float* U    = (const float*)d_in[3];
    const float* sf   = (const float*)d_in[4];
    const float* ell  = (const float*)d_in[5];
    float* out = (float*)d_out;
    float* ws  = (float*)d_ws;
    const int N = in_sizes[1] / 3;

    gp_precompute<<<1, 64, 0, stream>>>(Z, U, sf, ell, ws);

    const int PTS_PER_BLOCK = 256 * 4;
    const int blocks = (N + PTS_PER_BLOCK - 1) / PTS_PER_BLOCK;
    gp_forward<<<blocks, 256, 0, stream>>>(X, ws, ell, out, N);
}

// Round 6
// 54.030 us; speedup vs baseline: 2.2785x; 1.7517x over previous
//
#include <hip/hip_runtime.h>
#include <hip/hip_bf16.h>

#define LOG2E 1.4426950408889634f

#if __has_builtin(__builtin_amdgcn_exp2f)
#define EXP2F(x) __builtin_amdgcn_exp2f(x)
#else
#define EXP2F(x) exp2f(x)
#endif

// ---------------------------------------------------------------------------
// Kernel 1: ONE wave (64 threads). Register-resident Cholesky.
// Lane l owns row l of Kzz in r[0..63] (fully unrolled -> all register
// indices compile-time). Column-k broadcasts via __shfl with constant lane.
//
// R3 fix: __launch_bounds__(64, 1). R2's compiler default capped VGPRs at 64
// (8-wave occupancy target), so r[64]+rd[64] spilled to scratch (rocprof:
// FETCH_SIZE 63 KB, dur ~100 us). A 1-wave kernel needs no occupancy; with
// min-1-wave-per-EU the allocator may use the full register file (no spill
// through ~450 VGPRs, measured).
//
// ws layout (per m, 8 floats):
//   [0..2] = Z[m]/ell, [3] = -0.5*log2e*||Z[m]/ell||^2,
//   [4] = sf^2*W[m][0], [5] = sf^2*W[m][1], [6..7] = pad
// ---------------------------------------------------------------------------
__global__ __launch_bounds__(64, 1)
void gp_precompute(const float* __restrict__ Z, const float* __restrict__ U,
                   const float* __restrict__ sf_p, const float* __restrict__ ell_p,
                   float* __restrict__ ws) {
    __shared__ float Lsh[64 * 65];
    const int lane = threadIdx.x;          // 64 threads = 1 wave
    const float sf  = sf_p[0];
    const float ell = ell_p[0];
    const float inv_ell = 1.0f / ell;
    const float sf2 = sf * sf;

    const float z0 = Z[lane * 3 + 0] * inv_ell;
    const float z1 = Z[lane * 3 + 1] * inv_ell;
    const float z2 = Z[lane * 3 + 2] * inv_ell;

    // Row `lane` of Kzz, entirely in registers.
    float r[64];
#pragma unroll
    for (int j = 0; j < 64; ++j) {
        float dx = z0 - __shfl(z0, j);
        float dy = z1 - __shfl(z1, j);
        float dz = z2 - __shfl(z2, j);
        float sq = dx * dx + dy * dy + dz * dz;
        r[j] = sf2 * EXP2F(-0.5f * LOG2E * sq);
    }

    // Right-looking Cholesky, fully unrolled. After iteration k, r[k] on
    // lane l holds L[l][k] (valid for l >= k; upper-triangle garbage is
    // never read: shfl sources are always lanes j > k).
    float rd[64];                          // 1/L[k][k], uniform across lanes
#pragma unroll
    for (int k = 0; k < 64; ++k) {
        float dk  = __shfl(r[k], k);       // A[k][k]
        float inv = 1.0f / sqrtf(dk);
        rd[k] = inv;
        float lk = r[k] * inv;             // lane l: L[l][k]  (l>=k valid)
        r[k] = lk;
#pragma unroll
        for (int j = k + 1; j < 64; ++j) {
            float ljk = __shfl(lk, j);     // L[j][k], constant source lane
            r[j] = fmaf(-lk, ljk, r[j]);   // A[l][j] -= L[l][k]*L[j][k]
        }
    }

    // Spill L to LDS: row l at stride 65 -> both writes ((lane+j)%32) and
    // row-reads ((i+lane)%32) are conflict-free.
#pragma unroll
    for (int j = 0; j < 64; ++j) Lsh[lane * 65 + j] = r[j];
    __syncthreads();

    // Solve L^T W = U (column sweep): s_l = U[l][o] - sum_{j>i} L[j][l] W[j].
    float s0 = U[lane * 2 + 0];
    float s1 = U[lane * 2 + 1];
    float w0v = 0.0f, w1v = 0.0f;
#pragma unroll
    for (int i = 63; i >= 0; --i) {
        float w0 = __shfl(s0, i) * rd[i];  // W[i][0]
        float w1 = __shfl(s1, i) * rd[i];  // W[i][1]
        float a  = Lsh[i * 65 + lane];     // L[i][lane] (valid lane <= i)
        s0 = fmaf(-a, w0, s0);             // harmless garbage for lane >= i
        s1 = fmaf(-a, w1, s1);
        if (lane == i) { w0v = w0; w1v = w1; }
    }

    const float dm = -0.5f * LOG2E * (z0 * z0 + z1 * z1 + z2 * z2);
    ws[lane * 8 + 0] = z0;
    ws[lane * 8 + 1] = z1;
    ws[lane * 8 + 2] = z2;
    ws[lane * 8 + 3] = dm;
    ws[lane * 8 + 4] = sf2 * w0v;
    ws[lane * 8 + 5] = sf2 * w1v;
    ws[lane * 8 + 6] = 0.0f;
    ws[lane * 8 + 7] = 0.0f;
}

// ---------------------------------------------------------------------------
// Kernel 2 (byte-identical to R1/R2 -- getting its baseline counters this
// round): out[i,:] = sum_m sf^2*exp2(c_i + d_m + xt.z)*W[m,:]
// ---------------------------------------------------------------------------
__global__ __launch_bounds__(256) void gp_forward(const float* __restrict__ X,
                                                  const float* __restrict__ ws,
                                                  const float* __restrict__ ell_p,
                                                  float* __restrict__ out, int n) {
    __shared__ float4 P[128];   // 64 structs of {zs0,zs1,zs2,dm | w0,w1,0,0}
    for (int i = threadIdx.x; i < 128; i += 256)
        P[i] = ((const float4*)ws)[i];
    const float inv_ell = 1.0f / ell_p[0];
    __syncthreads();

    const int base = blockIdx.x * (256 * 4) + threadIdx.x;

    float xt0[4], xt1[4], xt2[4], c[4];
#pragma unroll
    for (int p = 0; p < 4; ++p) {
        int i = base + p * 256;
        int ii = (i < n) ? i : 0;            // clamp; result masked on store
        float xs0 = X[ii * 3 + 0] * inv_ell;
        float xs1 = X[ii * 3 + 1] * inv_ell;
        float xs2 = X[ii * 3 + 2] * inv_ell;
        c[p]  = -0.5f * LOG2E * (xs0 * xs0 + xs1 * xs1 + xs2 * xs2);
        xt0[p] = xs0 * LOG2E;
        xt1[p] = xs1 * LOG2E;
        xt2[p] = xs2 * LOG2E;
    }

    float acc0[4] = {0.f, 0.f, 0.f, 0.f};
    float acc1[4] = {0.f, 0.f, 0.f, 0.f};

#pragma unroll 4
    for (int m = 0; m < 64; ++m) {
        const float4 a = P[2 * m + 0];   // zs0, zs1, zs2, dm
        const float4 b = P[2 * m + 1];   // w0, w1, pad, pad
#pragma unroll
        for (int p = 0; p < 4; ++p) {
            float arg = fmaf(xt0[p], a.x,
                        fmaf(xt1[p], a.y,
                        fmaf(xt2[p], a.z, c[p] + a.w)));
            float e = EXP2F(arg);
            acc0[p] = fmaf(e, b.x, acc0[p]);
            acc1[p] = fmaf(e, b.y, acc1[p]);
        }
    }

    float2* out2 = (float2*)out;
#pragma unroll
    for (int p = 0; p < 4; ++p) {
        int i = base + p * 256;
        if (i < n) out2[i] = make_float2(acc0[p], acc1[p]);
    }
}

extern "C" void kernel_launch(void* const* d_in, const int* in_sizes, int n_in,
                              void* d_out, int out_size, void* d_ws, size_t ws_size,
                              hipStream_t stream) {
    // setup_inputs order: t, X, Z, U, sf, ell
    const float* X    = (const float*)d_in[1];
    const float* Z    = (const float*)d_in[2];
    const float* U    = (const float*)d_in[3];
    const float* sf   = (const float*)d_in[4];
    const float* ell  = (const float*)d_in[5];
    float* out = (float*)d_out;
    float* ws  = (float*)d_ws;
    const int N = in_sizes[1] / 3;

    gp_precompute<<<1, 64, 0, stream>>>(Z, U, sf, ell, ws);

    const int PTS_PER_BLOCK = 256 * 4;
    const int blocks = (N + PTS_PER_BLOCK - 1) / PTS_PER_BLOCK;
    gp_forward<<<blocks, 256, 0, stream>>>(X, ws, ell, out, N);
}